// Round 6
// baseline (312.782 us; speedup 1.0000x reference)
//
#include <hip/hip_runtime.h>

// Problem constants
#define MQ 8        // codebooks
#define KQ 4096     // codes per codebook
#define DG 64       // dims per group (D/M)
#define NN 32       // batch
#define HW 4096     // 64*64 spatial
#define DD 512      // output channels

typedef float f32x4 __attribute__((ext_vector_type(4)));

// ---------------------------------------------------------------------------
// Kernel 1: v[m,k,c] = sum_d codebook[m,k,d] * wv[m,c,d]
// Line-plane layout (round 5, verified):
//   v128[m][g2][k][c32]  (g2 = c>>5, c32 = c&31) — one k-row = 32 floats
//   = exactly one 128-B cache line.
// ---------------------------------------------------------------------------
__global__ __launch_bounds__(256) void compute_v_kernel(
    const float* __restrict__ codebook,
    const float* __restrict__ wv,
    float* __restrict__ v) {
  __shared__ float wv_t[DG][DG + 1];   // [d][c]
  __shared__ float cb[64][DG];         // [k_local][d]

  const int m = blockIdx.y;
  const int k0 = blockIdx.x * 64;
  const int tid = threadIdx.x;

  const float4* wvm4 = (const float4*)(wv + (size_t)m * DG * DG);
  for (int i = tid; i < DG * DG / 4; i += 256) {
    int c = i >> 4, d4 = (i & 15) * 4;
    float4 val = wvm4[i];
    wv_t[d4 + 0][c] = val.x;
    wv_t[d4 + 1][c] = val.y;
    wv_t[d4 + 2][c] = val.z;
    wv_t[d4 + 3][c] = val.w;
  }
  const float4* cbm4 = (const float4*)(codebook + ((size_t)m * KQ + k0) * DG);
  float4* cb4 = (float4*)&cb[0][0];
  for (int i = tid; i < 64 * DG / 4; i += 256) cb4[i] = cbm4[i];
  __syncthreads();

  const int c = tid & 63;
  const int kq = tid >> 6;

  float acc[16];
#pragma unroll
  for (int kl = 0; kl < 16; ++kl) acc[kl] = 0.f;

  for (int d4 = 0; d4 < DG; d4 += 4) {
    float w0 = wv_t[d4 + 0][c];
    float w1 = wv_t[d4 + 1][c];
    float w2 = wv_t[d4 + 2][c];
    float w3 = wv_t[d4 + 3][c];
#pragma unroll
    for (int kl = 0; kl < 16; ++kl) {
      float4 cbv = *(const float4*)&cb[kq * 16 + kl][d4];  // broadcast b128
      acc[kl] += cbv.x * w0 + cbv.y * w1 + cbv.z * w2 + cbv.w * w3;
    }
  }

  // line-plane store: v128[m][c>>5][k][c&31]
  float* vout = v + ((size_t)(m * 2 + (c >> 5)) * KQ) * 32 + (c & 31);
#pragma unroll
  for (int kl = 0; kl < 16; ++kl) {
    vout[(size_t)(k0 + kq * 16 + kl) * 32] = acc[kl];
  }
}

// ---------------------------------------------------------------------------
// Kernel 2 (round 6): oct-coalesced direct gather — IDENTICAL to round 5
// except stores are plain cached stores, not nontemporal.
// Round-5 postmortem: four structurally different gathers (LDS tile, LDS
// LUT, scattered direct, line-coalesced direct) all land at 85-90 us while
// the write floor is ~45 us -> the shared store path is the limiter.
// Theory: NT stores bypass L2 and hit HBM as scattered 128-B bursts at
// 16-KB stride (DRAM row-miss heavy); cached stores let L2 accumulate
// full dirty lines and evict in address-sorted streams (what fillBuffer
// does at 6.4 TB/s).  Single-variable A/B: drop NT.
// ---------------------------------------------------------------------------
__global__ __launch_bounds__(256, 4) void gather_oct_kernel(
    const int* __restrict__ codes,
    const float* __restrict__ v,
    float* __restrict__ out) {
  const int b = blockIdx.x;
  const int m = b & 7;                 // XCD round-robin
  const int chunk = (b >> 3) & 3;      // hw chunk of 1024
  const int n = b >> 5;                // 0..31

  const int tid = threadIdx.x;
  const int w = tid >> 6;              // wave 0..3
  const int l = tid & 63;              // lane
  const int oc8 = l >> 3;              // oct 0..7 (hw group)
  const int lo = l & 7;                // lane-in-oct (16-B chunk of row)

  const float* vm = v + (size_t)m * 2 * KQ * 32;   // v128[m]
  const int* cp = codes + (size_t)n * HW * MQ + m;
  float* ob = out + ((size_t)n * DD + m * DG) * HW;

  for (int p = 0; p < 8; ++p) {
    const int hwq = chunk * 1024 + p * 128 + w * 32 + oc8 * 4;  // oct's 4 hw
    int r[4];
#pragma unroll
    for (int t = 0; t < 4; ++t) r[t] = cp[(size_t)(hwq + t) * MQ];

#pragma unroll
    for (int g = 0; g < 2; ++g) {
      const float* plane = vm + (size_t)g * KQ * 32;
      f32x4 v0 = *(const f32x4*)(plane + (size_t)r[0] * 32 + lo * 4);
      f32x4 v1 = *(const f32x4*)(plane + (size_t)r[1] * 32 + lo * 4);
      f32x4 v2 = *(const f32x4*)(plane + (size_t)r[2] * 32 + lo * 4);
      f32x4 v3 = *(const f32x4*)(plane + (size_t)r[3] * 32 + lo * 4);
      f32x4 o0 = {v0.x, v1.x, v2.x, v3.x};
      f32x4 o1 = {v0.y, v1.y, v2.y, v3.y};
      f32x4 o2 = {v0.z, v1.z, v2.z, v3.z};
      f32x4 o3 = {v0.w, v1.w, v2.w, v3.w};
      // c = g*32 + lo*4 + e ; hw = hwq..hwq+3
      float* oc = ob + (size_t)(g * 32 + lo * 4) * HW + hwq;
      *(f32x4*)(oc + 0 * HW) = o0;
      *(f32x4*)(oc + 1 * HW) = o1;
      *(f32x4*)(oc + 2 * HW) = o2;
      *(f32x4*)(oc + 3 * HW) = o3;
    }
  }
}

extern "C" void kernel_launch(void* const* d_in, const int* in_sizes, int n_in,
                              void* d_out, int out_size, void* d_ws, size_t ws_size,
                              hipStream_t stream) {
  const int* codes = (const int*)d_in[0];        // (32,64,64,8) int32
  const float* codebook = (const float*)d_in[1]; // (8,4096,64) f32
  const float* wv = (const float*)d_in[2];       // (8,64,64) f32
  float* out = (float*)d_out;                    // (32,512,64,64) f32
  float* v = (float*)d_ws;                       // 8 MB scratch (line-plane v128)

  compute_v_kernel<<<dim3(64, 8), 256, 0, stream>>>(codebook, wv, v);
  gather_oct_kernel<<<NN * 4 * MQ, 256, 0, stream>>>(codes, v, out);
}